// Round 1
// baseline (843.113 us; speedup 1.0000x reference)
//
#include <hip/hip_runtime.h>

namespace {

constexpr int NV = 512;

// Total-order edge key matching the reference's stable sort:
// primary = float32 weight (non-negative -> bit pattern is order-monotone),
// secondary = np.triu_indices row-major index (the stable tie-break).
__device__ __forceinline__ unsigned long long edge_key(float w, int u, int v) {
    int i = u < v ? u : v;
    int j = u < v ? v : u;
    unsigned int idx = (unsigned int)(i * NV - (i * (i - 1)) / 2 + (j - i));
    return ((unsigned long long)__float_as_uint(w) << 32) | (unsigned long long)idx;
}

// Pull both matrices through L2 on every XCD so Prim's dependent row loads
// hit L2 (~200cy) instead of cold HBM (~900cy).
__global__ void prefetch_l2(const float* __restrict__ d1,
                            const float* __restrict__ d2,
                            float* __restrict__ ws) {
    const int total4 = NV * NV / 4; // float4 count per matrix
    float acc = 0.f;
    for (int i = blockIdx.x * blockDim.x + threadIdx.x; i < total4;
         i += gridDim.x * blockDim.x) {
        float4 a = reinterpret_cast<const float4*>(d1)[i];
        float4 b = reinterpret_cast<const float4*>(d2)[i];
        acc += a.x + a.w + b.x + b.w;
    }
    // keep loads live; branch is never taken with finite inputs
    if (acc == -1.0f) ws[16 + blockIdx.x] = acc;
}

// One wave per block; block 0 = MST of d1 (loss term vs d2), block 1 = MST of d2.
__global__ __launch_bounds__(64) void mst_loss(const float* __restrict__ d1,
                                               const float* __restrict__ d2,
                                               float* __restrict__ partial) {
    const float* __restrict__ Dm = (blockIdx.x == 0) ? d1 : d2;
    const float* __restrict__ Do = (blockIdx.x == 0) ? d2 : d1;
    const int lane = threadIdx.x;
    const unsigned long long INF = ~0ULL;

    // Each lane owns vertices v = lane + 64*j, j in [0,8)
    unsigned long long key[8];
    int from[8];

    // Tree starts at vertex 0.
#pragma unroll
    for (int j = 0; j < 8; ++j) {
        int v = lane + 64 * j;
        if (v == 0) { key[j] = INF; from[j] = 0; }
        else        { key[j] = edge_key(Dm[v], 0, v); from[j] = 0; }
    }

    for (int it = 0; it < NV - 1; ++it) {
        // local argmin over this lane's 8 vertices
        unsigned long long mk = key[0];
        int mv = lane;
#pragma unroll
        for (int j = 1; j < 8; ++j) {
            int v = lane + 64 * j;
            if (key[j] < mk) { mk = key[j]; mv = v; }
        }
        // 64-lane butterfly argmin; all lanes end with the global min
#pragma unroll
        for (int off = 32; off >= 1; off >>= 1) {
            unsigned long long ok = __shfl_xor(mk, off);
            int ov = __shfl_xor(mv, off);
            if (ok < mk) { mk = ok; mv = ov; }
        }
        // mv = newly added vertex; update keys from its row (coalesced loads)
        const float* __restrict__ row = Dm + (size_t)mv * NV;
#pragma unroll
        for (int j = 0; j < 8; ++j) {
            int v = lane + 64 * j;
            if (v == mv) {
                key[j] = INF; // entered tree; from[j] is now frozen = MST parent
            } else if (key[j] != INF) {
                unsigned long long k2 = edge_key(row[v], mv, v);
                if (k2 < key[j]) { key[j] = k2; from[j] = mv; }
            }
        }
    }

    // Every v != 0 contributes MST edge (from[v], v).
    float sum = 0.f;
#pragma unroll
    for (int j = 0; j < 8; ++j) {
        int v = lane + 64 * j;
        if (v != 0) {
            int u = from[j];
            float a = Dm[(size_t)u * NV + v];
            float b = Do[(size_t)u * NV + v];
            float d = a - b;
            sum += d * d;
        }
    }
#pragma unroll
    for (int off = 32; off >= 1; off >>= 1) sum += __shfl_xor(sum, off);
    if (lane == 0) partial[blockIdx.x] = sum;
}

__global__ void final_add(const float* __restrict__ partial, float* __restrict__ out) {
    out[0] = partial[0] + partial[1];
}

} // namespace

extern "C" void kernel_launch(void* const* d_in, const int* in_sizes, int n_in,
                              void* d_out, int out_size, void* d_ws, size_t ws_size,
                              hipStream_t stream) {
    const float* d1 = (const float*)d_in[0];
    const float* d2 = (const float*)d_in[1];
    float* out = (float*)d_out;
    float* ws = (float*)d_ws;

    prefetch_l2<<<128, 256, 0, stream>>>(d1, d2, ws);
    mst_loss<<<2, 64, 0, stream>>>(d1, d2, ws);      // writes ws[0], ws[1]
    final_add<<<1, 1, 0, stream>>>(ws, out);
}

// Round 2
// 374.732 us; speedup vs baseline: 2.2499x; 2.2499x over previous
//
#include <hip/hip_runtime.h>

namespace {

constexpr int NV = 512;
typedef unsigned long long ull;

// Total-order edge key matching the reference's stable sort:
// primary = float32 weight (non-negative -> bit pattern order-monotone),
// secondary = np.triu_indices row-major index (stable tie-break).
// Keys are globally unique (idx unique per edge).
__device__ __forceinline__ ull make_key(float w, int u, int v) {
    int i = u < v ? u : v;
    int j = u < v ? v : u;
    unsigned int idx = (unsigned int)(i * NV - (i * (i - 1)) / 2 + (j - i));
    return ((ull)__float_as_uint(w) << 32) | (ull)idx;
}

// One DPP min-reduce stage on a 64-bit key. old = x so masked/invalid lanes
// keep their own value (identity for min).
template <int CTRL, int ROW_MASK>
__device__ __forceinline__ ull dpp_min_u64(ull x) {
    int lo = (int)(unsigned)x;
    int hi = (int)(unsigned)(x >> 32);
    unsigned slo = (unsigned)__builtin_amdgcn_update_dpp(lo, lo, CTRL, ROW_MASK, 0xf, false);
    unsigned shi = (unsigned)__builtin_amdgcn_update_dpp(hi, hi, CTRL, ROW_MASK, 0xf, false);
    ull s = ((ull)shi << 32) | slo;
    return s < x ? s : x;
}

// Full wave64 min-reduce: result valid in lane 63 (LLVM atomic-optimizer seq).
__device__ __forceinline__ ull wave_min_u64(ull x) {
    x = dpp_min_u64<0x111, 0xf>(x); // row_shr:1
    x = dpp_min_u64<0x112, 0xf>(x); // row_shr:2
    x = dpp_min_u64<0x114, 0xf>(x); // row_shr:4
    x = dpp_min_u64<0x118, 0xf>(x); // row_shr:8
    x = dpp_min_u64<0x142, 0xa>(x); // row_bcast:15 -> rows 1,3
    x = dpp_min_u64<0x143, 0xc>(x); // row_bcast:31 -> rows 2,3
    unsigned mlo = (unsigned)__builtin_amdgcn_readlane((int)(unsigned)x, 63);
    unsigned mhi = (unsigned)__builtin_amdgcn_readlane((int)(unsigned)(x >> 32), 63);
    return ((ull)mhi << 32) | mlo;
}

// One wave per block; block 0 = MST of d1 (vs d2), block 1 = MST of d2 (vs d1).
__global__ __launch_bounds__(64) void mst_loss(const float* __restrict__ d1,
                                               const float* __restrict__ d2,
                                               float* __restrict__ partial) {
    const float* __restrict__ Dm = (blockIdx.x == 0) ? d1 : d2;
    const float* __restrict__ Do = (blockIdx.x == 0) ? d2 : d1;
    const int lane = threadIdx.x;
    const ull INF = ~0ULL;

    // ---- Warm the LOCAL XCD L2 with this block's matrix (1 MB), so the 511
    // dependent row loads below are ~200cy L2 hits instead of ~900cy HBM.
    {
        const float4* p4 = reinterpret_cast<const float4*>(Dm);
        float acc = 0.f;
#pragma unroll 8
        for (int base = 0; base < NV * NV / 4; base += 512) {
            float4 a0 = p4[base + lane];
            float4 a1 = p4[base + lane + 64];
            float4 a2 = p4[base + lane + 128];
            float4 a3 = p4[base + lane + 192];
            float4 a4 = p4[base + lane + 256];
            float4 a5 = p4[base + lane + 320];
            float4 a6 = p4[base + lane + 384];
            float4 a7 = p4[base + lane + 448];
            acc += a0.x + a1.x + a2.x + a3.x + a4.x + a5.x + a6.x + a7.x +
                   a0.w + a1.w + a2.w + a3.w + a4.w + a5.w + a6.w + a7.w;
        }
        if (acc == -1.0f) partial[8 + blockIdx.x] = acc; // keep loads live
    }

    // Each lane owns vertices v = lane + 64*j, j in [0,8)
    ull key[8];
    int from[8];

    // Tree starts at vertex 0.
#pragma unroll
    for (int j = 0; j < 8; ++j) {
        int v = lane + 64 * j;
        if (v == 0) { key[j] = INF; from[j] = 0; }
        else        { key[j] = make_key(Dm[v], 0, v); from[j] = 0; }
    }

    for (int it = 0; it < NV - 1; ++it) {
        // ---- local argmin over this lane's 8 vertices (depth-3 tree)
        ull k0 = key[0], k1 = key[1], k2 = key[2], k3 = key[3];
        ull k4 = key[4], k5 = key[5], k6 = key[6], k7 = key[7];
        int v0 = lane, v1 = lane + 64, v2 = lane + 128, v3 = lane + 192;
        int v4 = lane + 256, v5 = lane + 320, v6 = lane + 384, v7 = lane + 448;
        if (k1 < k0) { k0 = k1; v0 = v1; }
        if (k3 < k2) { k2 = k3; v2 = v3; }
        if (k5 < k4) { k4 = k5; v4 = v5; }
        if (k7 < k6) { k6 = k7; v6 = v7; }
        if (k2 < k0) { k0 = k2; v0 = v2; }
        if (k6 < k4) { k4 = k6; v4 = v6; }
        if (k4 < k0) { k0 = k4; v0 = v4; }
        const ull lmk = k0;
        const int lmv = v0;

        // ---- wave argmin: DPP min-reduce on key, then recover the (unique)
        // winning lane by ballot; mv lands in an SGPR via readlane.
        ull minkey = wave_min_u64(lmk);
        ull bal = __ballot(lmk == minkey);
        int winner = __ffsll(bal) - 1;
        int mv = __builtin_amdgcn_readlane(lmv, winner);

        // ---- update keys from row mv (scalar base + coalesced vector loads)
        const float* __restrict__ row = Dm + (size_t)mv * NV;
#pragma unroll
        for (int j = 0; j < 8; ++j) {
            int v = lane + 64 * j;
            float w = row[v];                    // unconditional, coalesced
            ull k2n = make_key(w, mv, v);
            bool inTree = (key[j] == INF);
            bool upd = !inTree && (v != mv) && (k2n < key[j]);
            key[j] = (v == mv) ? INF : (upd ? k2n : key[j]);
            from[j] = upd ? mv : from[j];
        }
    }

    // Every v != 0 contributes MST edge (from[v], v).
    float sum = 0.f;
#pragma unroll
    for (int j = 0; j < 8; ++j) {
        int v = lane + 64 * j;
        if (v != 0) {
            int u = from[j];
            float a = Dm[(size_t)u * NV + v];
            float b = Do[(size_t)u * NV + v];
            float d = a - b;
            sum += d * d;
        }
    }
#pragma unroll
    for (int off = 32; off >= 1; off >>= 1) sum += __shfl_xor(sum, off);
    if (lane == 0) partial[blockIdx.x] = sum;
}

__global__ void final_add(const float* __restrict__ partial, float* __restrict__ out) {
    out[0] = partial[0] + partial[1];
}

} // namespace

extern "C" void kernel_launch(void* const* d_in, const int* in_sizes, int n_in,
                              void* d_out, int out_size, void* d_ws, size_t ws_size,
                              hipStream_t stream) {
    const float* d1 = (const float*)d_in[0];
    const float* d2 = (const float*)d_in[1];
    float* out = (float*)d_out;
    float* ws = (float*)d_ws;

    mst_loss<<<2, 64, 0, stream>>>(d1, d2, ws);   // writes ws[0], ws[1]
    final_add<<<1, 1, 0, stream>>>(ws, out);
}

// Round 3
// 300.694 us; speedup vs baseline: 2.8039x; 1.2462x over previous
//
#include <hip/hip_runtime.h>

namespace {

constexpr int NV = 512;
typedef unsigned long long ull;
constexpr ull INF = ~0ULL;

// Tie-break: reference stable-sorts by (w, triu_idx). triu_idx is strictly
// monotone in lexicographic (i,j), i<=j (consecutive rows differ by +1), so
// (w_bits << 32) | (i<<9)|j induces the identical total order, and w>=0 makes
// float bits order-monotone. Keys are globally unique (distinct (i,j)).

template <int CTRL, int RM>
__device__ __forceinline__ unsigned dpp_min_u32(unsigned x) {
    unsigned s = (unsigned)__builtin_amdgcn_update_dpp((int)x, (int)x, CTRL, RM, 0xf, false);
    return s < x ? s : x;
}

// Wave64 min-reduce (LLVM atomic-optimizer DPP sequence), broadcast via lane 63.
__device__ __forceinline__ unsigned wave_min_u32(unsigned x) {
    x = dpp_min_u32<0x111, 0xf>(x); // row_shr:1
    x = dpp_min_u32<0x112, 0xf>(x); // row_shr:2
    x = dpp_min_u32<0x114, 0xf>(x); // row_shr:4
    x = dpp_min_u32<0x118, 0xf>(x); // row_shr:8
    x = dpp_min_u32<0x142, 0xa>(x); // row_bcast:15 -> rows 1,3
    x = dpp_min_u32<0x143, 0xc>(x); // row_bcast:31 -> rows 2,3
    return (unsigned)__builtin_amdgcn_readlane((int)x, 63);
}

// One wave per block; block 0 = MST of d1 (vs d2), block 1 = MST of d2 (vs d1).
__global__ __launch_bounds__(64) void mst_loss(const float* __restrict__ d1,
                                               const float* __restrict__ d2,
                                               float* __restrict__ partial) {
    const float* __restrict__ Dm = (blockIdx.x == 0) ? d1 : d2;
    const float* __restrict__ Do = (blockIdx.x == 0) ? d2 : d1;
    const int lane = threadIdx.x;
    const int vb = lane * 8; // this lane owns vertices vb..vb+7 (contiguous!)

    // ---- Warm the LOCAL XCD L2 with this block's matrix (1 MB) so the 511
    // dependent row loads are L2 hits.
    {
        const float4* p4 = reinterpret_cast<const float4*>(Dm);
        float acc = 0.f;
#pragma unroll 16
        for (int i = lane; i < NV * NV / 4; i += 64) {
            float4 a = p4[i];
            acc += a.x + a.w;
        }
        if (acc == -1.0f) partial[8 + blockIdx.x] = acc; // keep loads live
    }

    ull key[8];
    int from[8];

    // ---- init from row 0 (edges (0,v): i=0 -> low bits = v)
    {
        float4 ra = *reinterpret_cast<const float4*>(Dm + vb);
        float4 rb = *reinterpret_cast<const float4*>(Dm + vb + 4);
        float w[8] = {ra.x, ra.y, ra.z, ra.w, rb.x, rb.y, rb.z, rb.w};
#pragma unroll
        for (int k = 0; k < 8; ++k) {
            int v = vb + k;
            key[k] = ((ull)__float_as_uint(w[k]) << 32) | (unsigned)v;
            from[k] = 0;
        }
        if (lane == 0) key[0] = INF; // vertex 0 is the tree root
    }

    for (int it = 0; it < NV - 1; ++it) {
        // ---- local argmin over 8 owned vertices (depth-3 tree, u64 keys)
        ull k0 = key[0], k1 = key[1], k2 = key[2], k3 = key[3];
        ull k4 = key[4], k5 = key[5], k6 = key[6], k7 = key[7];
        int v0 = vb, v1 = vb + 1, v2 = vb + 2, v3 = vb + 3;
        int v4 = vb + 4, v5 = vb + 5, v6 = vb + 6, v7 = vb + 7;
        if (k1 < k0) { k0 = k1; v0 = v1; }
        if (k3 < k2) { k2 = k3; v2 = v3; }
        if (k5 < k4) { k4 = k5; v4 = v5; }
        if (k7 < k6) { k6 = k7; v6 = v7; }
        if (k2 < k0) { k0 = k2; v0 = v2; }
        if (k6 < k4) { k4 = k6; v4 = v6; }
        if (k4 < k0) { k0 = k4; v0 = v4; }
        const unsigned lw_hi = (unsigned)(k0 >> 32);
        const unsigned lw_lo = (unsigned)k0;

        // ---- wave argmin, two-phase 32-bit: reduce weight bits; resolve
        // ties (rare, uniform branch) by a second reduce on the low word.
        unsigned minw = wave_min_u32(lw_hi);
        ull eq = __ballot(lw_hi == minw);
        if (eq & (eq - 1)) { // >1 candidate lane: tie on weight bits
            unsigned ml = (lw_hi == minw) ? lw_lo : 0xFFFFFFFFu;
            unsigned minl = wave_min_u32(ml);
            eq = __ballot((lw_hi == minw) & (lw_lo == minl));
        }
        const int winner = __ffsll(eq) - 1;
        const int mv = __builtin_amdgcn_readlane(v0, winner); // SGPR-uniform

        // ---- update from row mv: whole row via 2x dwordx4 (SGPR base)
        const float* __restrict__ row = Dm + ((size_t)(unsigned)mv << 9);
        float4 ra = *reinterpret_cast<const float4*>(row + vb);
        float4 rb = *reinterpret_cast<const float4*>(row + vb + 4);
        float w[8] = {ra.x, ra.y, ra.z, ra.w, rb.x, rb.y, rb.z, rb.w};
#pragma unroll
        for (int k = 0; k < 8; ++k) {
            int v = vb + k;
            unsigned i = (unsigned)min(v, mv);
            unsigned j = (unsigned)max(v, mv);
            ull cand = ((ull)__float_as_uint(w[k]) << 32) | (ull)((i << 9) | j);
            bool upd = (cand < key[k]) & (key[k] != INF) & (v != mv);
            key[k] = (v == mv) ? INF : (upd ? cand : key[k]);
            from[k] = upd ? mv : from[k];
        }
    }

    // ---- every v != 0 contributes MST edge (from[v], v)
    float sum = 0.f;
#pragma unroll
    for (int k = 0; k < 8; ++k) {
        int v = vb + k;
        if (v != 0) {
            int u = from[k];
            float a = Dm[(size_t)u * NV + v];
            float b = Do[(size_t)u * NV + v];
            float d = a - b;
            sum += d * d;
        }
    }
#pragma unroll
    for (int off = 32; off >= 1; off >>= 1) sum += __shfl_xor(sum, off);
    if (lane == 0) partial[blockIdx.x] = sum;
}

__global__ void final_add(const float* __restrict__ partial, float* __restrict__ out) {
    out[0] = partial[0] + partial[1];
}

} // namespace

extern "C" void kernel_launch(void* const* d_in, const int* in_sizes, int n_in,
                              void* d_out, int out_size, void* d_ws, size_t ws_size,
                              hipStream_t stream) {
    const float* d1 = (const float*)d_in[0];
    const float* d2 = (const float*)d_in[1];
    float* out = (float*)d_out;
    float* ws = (float*)d_ws;

    mst_loss<<<2, 64, 0, stream>>>(d1, d2, ws); // writes ws[0], ws[1]
    final_add<<<1, 1, 0, stream>>>(ws, out);
}

// Round 4
// 97.285 us; speedup vs baseline: 8.6664x; 3.0908x over previous
//
#include <hip/hip_runtime.h>

namespace {

constexpr int NV = 512;
typedef unsigned long long ull;
constexpr ull INF64 = ~0ULL;

// Edge total order = reference's stable sort order: (f32 weight bits, triu
// index). triu index is order-isomorphic to lex (i,j), i<j, so the canonical
// 64-bit key  (w_bits<<32) | (i<<9) | j  induces the identical order; w>=0
// makes float bits order-monotone. Keys are globally unique -> the MST is
// unique -> Boruvka returns exactly the reference's (Kruskal's) edge set.
__global__ __launch_bounds__(1024) void boruvka_loss(
    const float* __restrict__ d1, const float* __restrict__ d2,
    float* __restrict__ partial)
{
    const int blk = blockIdx.x;
    const float* __restrict__ Dm = blk ? d2 : d1;
    const float* __restrict__ Do = blk ? d1 : d2;
    const int tid = threadIdx.x;

    __shared__ unsigned comp[NV];     // component id per vertex
    __shared__ ull      best[NV];     // per-component min outgoing edge key
    __shared__ unsigned parent[NV];   // union/contract scratch
    __shared__ int      accTot;       // accepted edges so far
    __shared__ float    red[1024];

    if (tid < NV) comp[tid] = tid;
    if (tid == 0) accTot = 0;

    float myContrib = 0.f;            // thread t accumulates for component t

    const int v  = tid >> 1;          // 2 threads per row
    const int c0 = (tid & 1) << 8;    // col base: 0 or 256
    const float* __restrict__ rowp = Dm + ((size_t)v << 9) + c0;

    for (int round = 0; round < 10; ++round) {
        if (tid < NV) best[tid] = INF64;
        __syncthreads();                       // comp/best stable for scan

        // ---- scan: per-thread min over 256 cols of row v (external edges)
        {
            const unsigned cv = comp[v];
            unsigned wmin = 0xFFFFFFFFu;       // weight bits
            unsigned umin = 0;                 // col of first (smallest-u) min
            bool any = false;
#pragma unroll 4
            for (int s = 0; s < 256; s += 4) {
                float4 w4 = *reinterpret_cast<const float4*>(rowp + s);
                uint4  q4 = *reinterpret_cast<const uint4*>(&comp[c0 + s]);
                unsigned wb;
                wb = __float_as_uint(w4.x);
                if ((q4.x != cv) && (!any || wb < wmin)) { wmin = wb; umin = c0 + s + 0; any = true; }
                wb = __float_as_uint(w4.y);
                if ((q4.y != cv) && (wb < wmin || !any)) { wmin = wb; umin = c0 + s + 1; any = true; }
                wb = __float_as_uint(w4.z);
                if ((q4.z != cv) && (wb < wmin || !any)) { wmin = wb; umin = c0 + s + 2; any = true; }
                wb = __float_as_uint(w4.w);
                if ((q4.w != cv) && (wb < wmin || !any)) { wmin = wb; umin = c0 + s + 3; any = true; }
            }
            if (any) {
                // ascending-u scan keeps the FIRST min -> within this row the
                // canonical tie-break is already satisfied; canonicalize and
                // let the u64 atomicMin resolve across rows/threads.
                unsigned uv = (unsigned)v;
                unsigned lo = (umin < uv) ? ((umin << 9) | uv) : ((uv << 9) | umin);
                atomicMin(&best[cv], ((ull)wmin << 32) | lo);
            }
        }
        __syncthreads();                       // best final

        // ---- hook: each component points at the component across its best edge
        if (tid < NV) {
            ull e = best[tid];
            unsigned p = tid;
            if (e != INF64) {
                unsigned lo = (unsigned)e & 0x3FFFFu;
                unsigned i = lo >> 9, j = lo & 511u;
                unsigned ci = comp[i], cj = comp[j];
                p = (ci == (unsigned)tid) ? cj : ci;
            }
            parent[tid] = p;
        }
        __syncthreads();

        // ---- break 2-cycles: smaller id of a mutual pair becomes root
        if (tid < NV) {
            unsigned p = parent[tid];
            if (p != (unsigned)tid && parent[p] == (unsigned)tid && (unsigned)tid < p)
                parent[tid] = tid;
        }
        __syncthreads();

        // ---- accept edges (dedup mutual picks by key equality)
        if (tid < NV) {
            ull e = best[tid];
            if (e != INF64) {
                unsigned lo = (unsigned)e & 0x3FFFFu;
                unsigned i = lo >> 9, j = lo & 511u;
                unsigned ci = comp[i], cj = comp[j];
                unsigned p = (ci == (unsigned)tid) ? cj : ci;
                bool dup = (best[p] == e) && (p < (unsigned)tid);
                if (!dup) {
                    float a  = __uint_as_float((unsigned)(e >> 32)); // Dm[i][j]
                    float bo = Do[(size_t)i * NV + j];
                    float d = a - bo;
                    myContrib += d * d;
                    atomicAdd(&accTot, 1);
                }
            }
        }

        // ---- pointer jumping to roots (doubling; races only accelerate)
        for (int jt = 0; jt < 9; ++jt) {
            __syncthreads();
            if (tid < NV) parent[tid] = parent[parent[tid]];
        }
        __syncthreads();

        // ---- relabel vertices
        if (tid < NV) comp[tid] = parent[comp[tid]];
        __syncthreads();

        if (accTot == NV - 1) break;           // uniform (LDS read post-barrier)
    }

    // ---- deterministic fixed-order tree reduction of contributions
    red[tid] = myContrib;
    for (int off = 512; off >= 1; off >>= 1) {
        __syncthreads();
        if (tid < off) red[tid] += red[tid + off];
    }
    if (tid == 0) partial[blk] = red[0];
}

__global__ void final_add(const float* __restrict__ partial, float* __restrict__ out) {
    out[0] = partial[0] + partial[1];
}

} // namespace

extern "C" void kernel_launch(void* const* d_in, const int* in_sizes, int n_in,
                              void* d_out, int out_size, void* d_ws, size_t ws_size,
                              hipStream_t stream) {
    const float* d1 = (const float*)d_in[0];
    const float* d2 = (const float*)d_in[1];
    float* out = (float*)d_out;
    float* ws = (float*)d_ws;

    boruvka_loss<<<2, 1024, 0, stream>>>(d1, d2, ws); // writes ws[0], ws[1]
    final_add<<<1, 1, 0, stream>>>(ws, out);
}